// Round 6
// baseline (288.076 us; speedup 1.0000x reference)
//
#include <hip/hip_runtime.h>
#include <hip/hip_bf16.h>
#include <math.h>

#define MAXO 16

// ---------------------------------------------------------------------------
// m1: IoU over (b, d-chunk). Per-default argmax over objects (first-wins) ->
//     tcls/ovl. Per-object argmax over defaults reduced block-locally, written
//     non-atomically to key64c[b][c][o]. Also inits scalar accumulators.
// ---------------------------------------------------------------------------
__global__ __launch_bounds__(256, 2)
void m1_kernel(const float* __restrict__ boxes,   // [B,O,4] xy
               const float* __restrict__ dboxes,  // [D,4] cxcy
               int*   __restrict__ tcls,          // [B,D] obj idx
               float* __restrict__ ovl,           // [B,D] best iou
               unsigned long long* __restrict__ key64c, // [B,CH,O]
               int*    __restrict__ n_pos,
               double* __restrict__ loc_sum,
               double* __restrict__ pos_sum,
               double* __restrict__ neg_sum,
               int*    __restrict__ npt,
               int*    __restrict__ counter,
               int D, int O, int CH, int chunk) {
    int b = blockIdx.x / CH, c = blockIdx.x % CH;
    int t = threadIdx.x;

    if (c == 0) {
        if (t == 0) n_pos[b] = 0;
        if (b == 0) {
            if (t == 1) *loc_sum = 0.0;
            if (t == 2) *pos_sum = 0.0;
            if (t == 3) *neg_sum = 0.0;
            if (t == 4) *npt = 0;
            if (t == 5) *counter = 0;
        }
    }

    __shared__ float sbox[MAXO][4];
    __shared__ float sarea[MAXO];
    __shared__ unsigned long long skey[4][MAXO];
    if (t < O) {
        const float* bp = boxes + ((size_t)b * O + t) * 4;
        float x1 = bp[0], y1 = bp[1], x2 = bp[2], y2 = bp[3];
        sbox[t][0] = x1; sbox[t][1] = y1; sbox[t][2] = x2; sbox[t][3] = y2;
        sarea[t] = (x2 - x1) * (y2 - y1);
    }
    __syncthreads();

    unsigned long long bestk[MAXO];
#pragma unroll
    for (int o = 0; o < MAXO; ++o) bestk[o] = 0ull;

    size_t rowoff = (size_t)b * D;
    int d0 = c * chunk, d1 = min(D, d0 + chunk);

    for (int d = d0 + t; d < d1; d += 256) {
        float4 db = ((const float4*)dboxes)[d];
        float dx1 = db.x - db.z * 0.5f, dy1 = db.y - db.w * 0.5f;
        float dx2 = db.x + db.z * 0.5f, dy2 = db.y + db.w * 0.5f;
        float a2 = (dx2 - dx1) * (dy2 - dy1);
        unsigned notd = 0xFFFFFFFFu - (unsigned)d;
        float mval = -1.0f; int mobj = 0;
#pragma unroll
        for (int o = 0; o < MAXO; ++o) {
            if (o < O) {
                float lx = fmaxf(sbox[o][0], dx1), ly = fmaxf(sbox[o][1], dy1);
                float rx = fminf(sbox[o][2], dx2), ry = fminf(sbox[o][3], dy2);
                float w = fmaxf(rx - lx, 0.0f), h = fmaxf(ry - ly, 0.0f);
                float inter = w * h;
                float iou = inter / (sarea[o] + a2 - inter);
                if (iou > mval) { mval = iou; mobj = o; }   // first-wins over o
                unsigned long long key =
                    ((unsigned long long)__float_as_uint(iou) << 32) |
                    (unsigned long long)notd;               // max iou, lowest d
                if (key > bestk[o]) bestk[o] = key;
            }
        }
        tcls[rowoff + d] = mobj;
        ovl[rowoff + d]  = mval;
    }

    int w = t >> 6;
#pragma unroll
    for (int o = 0; o < MAXO; ++o) {
        if (o < O) {
            unsigned long long k = bestk[o];
            for (int s = 32; s > 0; s >>= 1) {
                unsigned long long k2 =
                    (unsigned long long)__shfl_xor((long long)k, s);
                if (k2 > k) k = k2;
            }
            if ((t & 63) == 0) skey[w][o] = k;
        }
    }
    __syncthreads();
    if (t < O) {
        unsigned long long k = skey[0][t];
#pragma unroll
        for (int i = 1; i < 4; ++i) {
            unsigned long long k2 = skey[i][t];
            if (k2 > k) k = k2;
        }
        key64c[((size_t)b * CH + c) * O + t] = k;
    }
}

// ---------------------------------------------------------------------------
// m2r: reduce key64c over chunks -> dstar[b][o] (tiny)
// ---------------------------------------------------------------------------
__global__ void m2r_kernel(const unsigned long long* __restrict__ key64c,
                           int* __restrict__ dstar, int B, int O, int CH) {
    int n = B * O;
    for (int idx = threadIdx.x; idx < n; idx += blockDim.x) {
        int b = idx / O, o = idx % O;
        unsigned long long k = 0ull;
        for (int c = 0; c < CH; ++c) {
            unsigned long long k2 = key64c[((size_t)b * CH + c) * O + o];
            if (k2 > k) k = k2;
        }
        dstar[idx] = (int)(0xFFFFFFFFu - (unsigned)(k & 0xFFFFFFFFull));
    }
}

// ---------------------------------------------------------------------------
// m3: labels (override inline, ascending scan = last-wins), encode + smoothL1
// ---------------------------------------------------------------------------
__global__ void m3_kernel(const float* __restrict__ boxes,
                          const int*   __restrict__ labels,
                          const float* __restrict__ dboxes,
                          const float* __restrict__ locs,
                          int*   __restrict__ tcls,
                          const float* __restrict__ ovl,
                          const int*   __restrict__ dstar, // [B,O]
                          int*   __restrict__ n_pos,
                          double* __restrict__ loc_sum,
                          int*   __restrict__ npt,
                          int D, int O, int CHm) {
    int b = blockIdx.x / CHm, c = blockIdx.x % CHm;
    int t = threadIdx.x;
    int d = c * 256 + t;

    __shared__ float sbox[MAXO][4];
    __shared__ int   slab[MAXO];
    __shared__ int   sdstar[MAXO];
    __shared__ double sred[256];
    __shared__ int    sredi[256];
    if (t < O) {
        const float* bp = boxes + ((size_t)b * O + t) * 4;
        sbox[t][0] = bp[0]; sbox[t][1] = bp[1]; sbox[t][2] = bp[2]; sbox[t][3] = bp[3];
        slab[t] = labels[(size_t)b * O + t];
        sdstar[t] = dstar[(size_t)b * O + t];
    }
    __syncthreads();

    double acc = 0.0;
    int cnt = 0;
    if (d < D) {
        size_t rowoff = (size_t)b * D;
        int o = tcls[rowoff + d];
        float ov = ovl[rowoff + d];
#pragma unroll
        for (int oo = 0; oo < MAXO; ++oo) {
            if (oo < O && sdstar[oo] == d) { o = oo; ov = 1.0f; }
        }
        int lab = (ov < 0.5f) ? 0 : slab[o];
        tcls[rowoff + d] = lab;
        if (lab != 0) {
            cnt = 1;
            float x1 = sbox[o][0], y1 = sbox[o][1], x2 = sbox[o][2], y2 = sbox[o][3];
            float cx = (x1 + x2) * 0.5f, cy = (y1 + y2) * 0.5f;
            float w = x2 - x1, h = y2 - y1;
            float4 db = ((const float4*)dboxes)[d];
            float g0 = (cx - db.x) / (db.z * 0.1f);
            float g1 = (cy - db.y) / (db.w * 0.1f);
            float g2 = __logf(w / db.z) * 5.0f;
            float g3 = __logf(h / db.w) * 5.0f;
            float4 lp = ((const float4*)locs)[rowoff + d];
            float dd;
            dd = fabsf(lp.x - g0); acc += (dd < 1.0f) ? 0.5f * dd * dd : dd - 0.5f;
            dd = fabsf(lp.y - g1); acc += (dd < 1.0f) ? 0.5f * dd * dd : dd - 0.5f;
            dd = fabsf(lp.z - g2); acc += (dd < 1.0f) ? 0.5f * dd * dd : dd - 0.5f;
            dd = fabsf(lp.w - g3); acc += (dd < 1.0f) ? 0.5f * dd * dd : dd - 0.5f;
        }
    }
    sred[t] = acc; sredi[t] = cnt;
    __syncthreads();
    for (int s = 128; s > 0; s >>= 1) {
        if (t < s) { sred[t] += sred[t + s]; sredi[t] += sredi[t + s]; }
        __syncthreads();
    }
    if (t == 0) {
        if (sredi[0]) { atomicAdd(&n_pos[b], sredi[0]); atomicAdd(npt, sredi[0]); }
        if (sred[0] != 0.0) atomicAdd(loc_sum, sred[0]);
    }
}

// ---------------------------------------------------------------------------
// ce2: wave-per-row, 2 rows/iteration (ILP), direct global loads, C <= 128
// ---------------------------------------------------------------------------
__global__ __launch_bounds__(256, 8)
void ce2_kernel(const float* __restrict__ cls, const int* __restrict__ tcls,
                float* __restrict__ negbuf, double* __restrict__ pos_sum,
                int R, int C) {
    int lane = threadIdx.x & 63;
    int wid  = (blockIdx.x * blockDim.x + threadIdx.x) >> 6;
    int nw   = (gridDim.x * blockDim.x) >> 6;
    double acc = 0.0;

    for (int r0 = wid * 2; r0 < R; r0 += nw * 2) {
        int r1 = r0 + 1;
        bool has1 = (r1 < R);
        const float* A  = cls + (size_t)r0 * C;
        const float* Bp = cls + (size_t)r1 * C;
        float a0 = (lane < C) ? A[lane] : -INFINITY;
        float a1 = (64 + lane < C) ? A[64 + lane] : -INFINITY;
        float b0 = (has1 && lane < C) ? Bp[lane] : -INFINITY;
        float b1 = (has1 && 64 + lane < C) ? Bp[64 + lane] : -INFINITY;
        int ta = tcls[r0];
        int tb = has1 ? tcls[r1] : 0;

        float ma = fmaxf(a0, a1), mb = fmaxf(b0, b1);
#pragma unroll
        for (int s = 32; s > 0; s >>= 1) {
            ma = fmaxf(ma, __shfl_xor(ma, s));
            mb = fmaxf(mb, __shfl_xor(mb, s));
        }
        float ea = __expf(a0 - ma) + __expf(a1 - ma);   // exp(-inf)=0
        float eb = __expf(b0 - mb) + __expf(b1 - mb);
#pragma unroll
        for (int s = 32; s > 0; s >>= 1) {
            ea += __shfl_xor(ea, s);
            eb += __shfl_xor(eb, s);
        }
        int sa = (ta < 64) ? ta : ta - 64;
        int sb = (tb < 64) ? tb : tb - 64;
        float xa0 = __shfl(a0, sa), xa1 = __shfl(a1, sa);
        float xb0 = __shfl(b0, sb), xb1 = __shfl(b1, sb);
        float lta = (ta < 64) ? xa0 : xa1;
        float ltb = (tb < 64) ? xb0 : xb1;
        float cea = fmaxf(__logf(ea) + ma - lta, 0.0f);
        float ceb = fmaxf(__logf(eb) + mb - ltb, 0.0f);
        if (lane == 0) {
            if (ta != 0) { acc += (double)cea; negbuf[r0] = 0.0f; }
            else         { negbuf[r0] = cea; }
            if (has1) {
                if (tb != 0) { acc += (double)ceb; negbuf[r1] = 0.0f; }
                else         { negbuf[r1] = ceb; }
            }
        }
    }
    if (lane == 0 && acc != 0.0) atomicAdd(pos_sum, acc);
}

// ---------------------------------------------------------------------------
// ce fallback (C > 128): wave per row, strided
// ---------------------------------------------------------------------------
__global__ void ce_kernel(const float* __restrict__ cls, const int* __restrict__ tcls,
                          float* __restrict__ negbuf, double* __restrict__ pos_sum,
                          int R, int C) {
    int gid  = blockIdx.x * blockDim.x + threadIdx.x;
    int wid  = gid >> 6, lane = threadIdx.x & 63;
    int nw   = (gridDim.x * blockDim.x) >> 6;
    double acc = 0.0;
    for (int r = wid; r < R; r += nw) {
        const float* base = cls + (size_t)r * C;
        float m = -INFINITY;
        for (int i = lane; i < C; i += 64) m = fmaxf(m, base[i]);
        for (int s = 32; s > 0; s >>= 1) m = fmaxf(m, __shfl_xor(m, s));
        float e = 0.0f;
        for (int i = lane; i < C; i += 64) e += __expf(base[i] - m);
        for (int s = 32; s > 0; s >>= 1) e += __shfl_xor(e, s);
        int tgt = tcls[r];
        float ce = fmaxf(__logf(e) + m - base[tgt], 0.0f);
        if (lane == 0) {
            if (tgt != 0) { acc += (double)ce; negbuf[r] = 0.0f; }
            else          { negbuf[r] = ce; }
        }
    }
    if (lane == 0 && acc != 0.0) atomicAdd(pos_sum, acc);
}

// ---------------------------------------------------------------------------
// hardneg (+ fused finalize): exact top-k sum via byte radix-select.
// Histograms: 4 per-wave replicas (count + value-sum). Boundary search via
// PARALLEL 8-step suffix scan (was: serial 256-bin scan at LDS latency).
// ---------------------------------------------------------------------------
__global__ __launch_bounds__(256) void hardneg_kernel(
        const float* __restrict__ neg, const int* __restrict__ n_pos,
        double* __restrict__ neg_sum, const int* __restrict__ npt,
        const double* __restrict__ loc_sum, const double* __restrict__ pos_sum,
        int* __restrict__ counter, float* __restrict__ out,
        int D, int uselds) {
    extern __shared__ float ldsrow[];               // D floats (if uselds)
    int b = blockIdx.x, t = threadIdx.x;
    int w = t >> 6;
    const float* row = neg + (size_t)b * D;

    __shared__ unsigned bins[4][256];
    __shared__ float    fbins[4][256];
    __shared__ unsigned sc[2][256];
    __shared__ float    sf[2][256];
    __shared__ unsigned sh_kk, sh_prefix, sh_pmask;
    __shared__ double   sh_above;

    int k0 = 3 * n_pos[b];
    if (k0 > D) k0 = D;
    if (t == 0) { sh_kk = (unsigned)k0; sh_prefix = 0u; sh_pmask = 0u; sh_above = 0.0; }
    __syncthreads();

    if (k0 > 0) {
        for (int shift = 24; shift >= 0; shift -= 8) {
#pragma unroll
            for (int i = 0; i < 4; ++i) { bins[i][t] = 0; fbins[i][t] = 0.0f; }
            __syncthreads();
            unsigned pmask = sh_pmask, prefix = sh_prefix;
            unsigned kk = sh_kk;
            if (shift == 24) {                       // first pass: global -> LDS
                for (int i = t; i < D; i += 256) {
                    float fv = row[i];
                    if (uselds) ldsrow[i] = fv;
                    unsigned v = __float_as_uint(fv);
                    atomicAdd(&bins[w][v >> 24], 1u);
                    atomicAdd(&fbins[w][v >> 24], fv);
                }
            } else {
                for (int i = t; i < D; i += 256) {
                    float fv = uselds ? ldsrow[i] : row[i];
                    unsigned v = __float_as_uint(fv);
                    if ((v & pmask) == prefix) {
                        atomicAdd(&bins[w][(v >> shift) & 255u], 1u);
                        atomicAdd(&fbins[w][(v >> shift) & 255u], fv);
                    }
                }
            }
            __syncthreads();
            // merge replicas
            sc[0][t] = bins[0][t] + bins[1][t] + bins[2][t] + bins[3][t];
            sf[0][t] = fbins[0][t] + fbins[1][t] + fbins[2][t] + fbins[3][t];
            __syncthreads();
            // inclusive suffix scan, 8 ping-pong steps
            int src = 0;
#pragma unroll
            for (int off = 1; off < 256; off <<= 1) {
                int dst = 1 - src;
                unsigned cv = sc[src][t] + ((t + off < 256) ? sc[src][t + off] : 0u);
                float    fv = sf[src][t] + ((t + off < 256) ? sf[src][t + off] : 0.0f);
                sc[dst][t] = cv; sf[dst][t] = fv;
                __syncthreads();
                src = dst;
            }
            // boundary: unique t with sufc[t] >= kk && sufc[t+1] < kk
            unsigned sufc  = sc[src][t];
            unsigned above = (t < 255) ? sc[src][t + 1] : 0u;
            if (sufc >= kk && above < kk) {
                sh_above += (double)((t < 255) ? sf[src][t + 1] : 0.0f);
                sh_kk = kk - above;
                sh_prefix = prefix | ((unsigned)t << shift);
                sh_pmask = pmask | (255u << shift);
            }
            __syncthreads();
        }
        if (t == 0) {
            double tot = sh_above +
                (double)sh_kk * (double)__uint_as_float(sh_prefix);
            if (tot != 0.0) atomicAdd(neg_sum, tot);
        }
    }

    // fused finalize: last block writes outputs
    __threadfence();
    if (t == 0) {
        int done = atomicAdd(counter, 1);
        if (done == (int)gridDim.x - 1) {
            double ls = atomicAdd((double*)loc_sum, 0.0);
            double ps = atomicAdd((double*)pos_sum, 0.0);
            double ns = atomicAdd(neg_sum, 0.0);
            int    n  = atomicAdd((int*)npt, 0);
            double nd = (double)n;
            out[0] = (float)(ls / (nd * 4.0));
            out[1] = (float)((ns + ps) / nd);
        }
    }
}

// ---------------------------------------------------------------------------
extern "C" void kernel_launch(void* const* d_in, const int* in_sizes, int n_in,
                              void* d_out, int out_size, void* d_ws, size_t ws_size,
                              hipStream_t stream) {
    const float* locs   = (const float*)d_in[0];
    const float* cls    = (const float*)d_in[1];
    const float* boxes  = (const float*)d_in[2];
    const int*   labels = (const int*)d_in[3];
    const float* dboxes = (const float*)d_in[4];

    int D = in_sizes[4] / 4;
    int B = in_sizes[0] / (4 * D);
    int O = in_sizes[3] / B;
    int C = in_sizes[1] / (B * D);
    int R = B * D;

    const int chunk = 1024;
    int CH1 = (D + chunk - 1) / chunk;
    int CHm = (D + 255) / 256;

    char* ws = (char*)d_ws;
    double* loc_sum = (double*)ws;                    // [0,8)
    double* pos_sum = loc_sum + 1;                    // [8,16)
    double* neg_sum = loc_sum + 2;                    // [16,24)
    int*    npt     = (int*)(ws + 24);                // [24,28)
    int*    counter = (int*)(ws + 28);                // [28,32)
    size_t off = 32;
    int* n_pos = (int*)(ws + off); off += (size_t)B * 4;
    int* dstar = (int*)(ws + off); off += (size_t)B * O * 4;
    off = (off + 7) & ~(size_t)7;
    unsigned long long* key64c = (unsigned long long*)(ws + off);
    off += (size_t)B * CH1 * O * 8;
    off = (off + 15) & ~(size_t)15;
    int*   tcls   = (int*)(ws + off); off += (size_t)R * 4;
    float* negbuf = (float*)(ws + off);

    m1_kernel<<<B * CH1, 256, 0, stream>>>(boxes, dboxes, tcls, negbuf /*ovl*/,
                                           key64c, n_pos, loc_sum, pos_sum, neg_sum,
                                           npt, counter, D, O, CH1, chunk);
    m2r_kernel<<<1, 256, 0, stream>>>(key64c, dstar, B, O, CH1);
    m3_kernel<<<B * CHm, 256, 0, stream>>>(boxes, labels, dboxes, locs, tcls, negbuf,
                                           dstar, n_pos, loc_sum, npt, D, O, CHm);
    if (C <= 128) {
        ce2_kernel<<<2048, 256, 0, stream>>>(cls, tcls, negbuf, pos_sum, R, C);
    } else {
        ce_kernel<<<2048, 256, 0, stream>>>(cls, tcls, negbuf, pos_sum, R, C);
    }
    int uselds = (D * 4 <= 40000) ? 1 : 0;
    size_t shbytes = uselds ? (size_t)D * 4 : 0;
    hardneg_kernel<<<B, 256, shbytes, stream>>>(negbuf, n_pos, neg_sum, npt,
                                                loc_sum, pos_sum, counter,
                                                (float*)d_out, D, uselds);
}

// Round 7
// 250.778 us; speedup vs baseline: 1.1487x; 1.1487x over previous
//
#include <hip/hip_runtime.h>
#include <hip/hip_bf16.h>
#include <math.h>

#define MAXO 16

// ---------------------------------------------------------------------------
// m1: IoU over (b, d-chunk). Per-default argmax over objects (first-wins) ->
//     tcls/ovl. Per-object argmax over defaults reduced block-locally, written
//     non-atomically to key64c[b][c][o]. Also inits scalar accumulators.
// ---------------------------------------------------------------------------
__global__ __launch_bounds__(256, 2)
void m1_kernel(const float* __restrict__ boxes,   // [B,O,4] xy
               const float* __restrict__ dboxes,  // [D,4] cxcy
               int*   __restrict__ tcls,          // [B,D] obj idx
               float* __restrict__ ovl,           // [B,D] best iou
               unsigned long long* __restrict__ key64c, // [B,CH,O]
               int*    __restrict__ n_pos,
               double* __restrict__ loc_sum,
               double* __restrict__ pos_sum,
               double* __restrict__ neg_sum,
               int*    __restrict__ npt,
               int*    __restrict__ counter,
               int D, int O, int CH, int chunk) {
    int b = blockIdx.x / CH, c = blockIdx.x % CH;
    int t = threadIdx.x;

    if (c == 0) {
        if (t == 0) n_pos[b] = 0;
        if (b == 0) {
            if (t == 1) *loc_sum = 0.0;
            if (t == 2) *pos_sum = 0.0;
            if (t == 3) *neg_sum = 0.0;
            if (t == 4) *npt = 0;
            if (t == 5) *counter = 0;
        }
    }

    __shared__ float sbox[MAXO][4];
    __shared__ float sarea[MAXO];
    __shared__ unsigned long long skey[4][MAXO];
    if (t < O) {
        const float* bp = boxes + ((size_t)b * O + t) * 4;
        float x1 = bp[0], y1 = bp[1], x2 = bp[2], y2 = bp[3];
        sbox[t][0] = x1; sbox[t][1] = y1; sbox[t][2] = x2; sbox[t][3] = y2;
        sarea[t] = (x2 - x1) * (y2 - y1);
    }
    __syncthreads();

    unsigned long long bestk[MAXO];
#pragma unroll
    for (int o = 0; o < MAXO; ++o) bestk[o] = 0ull;

    size_t rowoff = (size_t)b * D;
    int d0 = c * chunk, d1 = min(D, d0 + chunk);

    for (int d = d0 + t; d < d1; d += 256) {
        float4 db = ((const float4*)dboxes)[d];
        float dx1 = db.x - db.z * 0.5f, dy1 = db.y - db.w * 0.5f;
        float dx2 = db.x + db.z * 0.5f, dy2 = db.y + db.w * 0.5f;
        float a2 = (dx2 - dx1) * (dy2 - dy1);
        unsigned notd = 0xFFFFFFFFu - (unsigned)d;
        float mval = -1.0f; int mobj = 0;
#pragma unroll
        for (int o = 0; o < MAXO; ++o) {
            if (o < O) {
                float lx = fmaxf(sbox[o][0], dx1), ly = fmaxf(sbox[o][1], dy1);
                float rx = fminf(sbox[o][2], dx2), ry = fminf(sbox[o][3], dy2);
                float w = fmaxf(rx - lx, 0.0f), h = fmaxf(ry - ly, 0.0f);
                float inter = w * h;
                float iou = inter / (sarea[o] + a2 - inter);
                if (iou > mval) { mval = iou; mobj = o; }   // first-wins over o
                unsigned long long key =
                    ((unsigned long long)__float_as_uint(iou) << 32) |
                    (unsigned long long)notd;               // max iou, lowest d
                if (key > bestk[o]) bestk[o] = key;
            }
        }
        tcls[rowoff + d] = mobj;
        ovl[rowoff + d]  = mval;
    }

    int w = t >> 6;
#pragma unroll
    for (int o = 0; o < MAXO; ++o) {
        if (o < O) {
            unsigned long long k = bestk[o];
            for (int s = 32; s > 0; s >>= 1) {
                unsigned long long k2 =
                    (unsigned long long)__shfl_xor((long long)k, s);
                if (k2 > k) k = k2;
            }
            if ((t & 63) == 0) skey[w][o] = k;
        }
    }
    __syncthreads();
    if (t < O) {
        unsigned long long k = skey[0][t];
#pragma unroll
        for (int i = 1; i < 4; ++i) {
            unsigned long long k2 = skey[i][t];
            if (k2 > k) k = k2;
        }
        key64c[((size_t)b * CH + c) * O + t] = k;
    }
}

// ---------------------------------------------------------------------------
// m3: chunk-key reduce inline (m2r folded in), labels (override inline,
//     ascending scan = last-wins), encode + smooth-L1; n_pos / npt / loc_sum
// ---------------------------------------------------------------------------
__global__ void m3_kernel(const float* __restrict__ boxes,
                          const int*   __restrict__ labels,
                          const float* __restrict__ dboxes,
                          const float* __restrict__ locs,
                          int*   __restrict__ tcls,
                          const float* __restrict__ ovl,
                          const unsigned long long* __restrict__ key64c, // [B,CH,O]
                          int*   __restrict__ n_pos,
                          double* __restrict__ loc_sum,
                          int*   __restrict__ npt,
                          int D, int O, int CH, int CHm) {
    int b = blockIdx.x / CHm, c = blockIdx.x % CHm;
    int t = threadIdx.x;
    int d = c * 256 + t;

    __shared__ float sbox[MAXO][4];
    __shared__ int   slab[MAXO];
    __shared__ int   sdstar[MAXO];
    __shared__ double sred[256];
    __shared__ int    sredi[256];
    if (t < O) {
        const float* bp = boxes + ((size_t)b * O + t) * 4;
        sbox[t][0] = bp[0]; sbox[t][1] = bp[1]; sbox[t][2] = bp[2]; sbox[t][3] = bp[3];
        slab[t] = labels[(size_t)b * O + t];
        unsigned long long k = 0ull;
        for (int cc = 0; cc < CH; ++cc) {
            unsigned long long k2 = key64c[((size_t)b * CH + cc) * O + t];
            if (k2 > k) k = k2;
        }
        sdstar[t] = (int)(0xFFFFFFFFu - (unsigned)(k & 0xFFFFFFFFull));
    }
    __syncthreads();

    double acc = 0.0;
    int cnt = 0;
    if (d < D) {
        size_t rowoff = (size_t)b * D;
        int o = tcls[rowoff + d];
        float ov = ovl[rowoff + d];
#pragma unroll
        for (int oo = 0; oo < MAXO; ++oo) {        // ascending -> last-write-wins
            if (oo < O && sdstar[oo] == d) { o = oo; ov = 1.0f; }
        }
        int lab = (ov < 0.5f) ? 0 : slab[o];
        tcls[rowoff + d] = lab;
        if (lab != 0) {
            cnt = 1;
            float x1 = sbox[o][0], y1 = sbox[o][1], x2 = sbox[o][2], y2 = sbox[o][3];
            float cx = (x1 + x2) * 0.5f, cy = (y1 + y2) * 0.5f;
            float w = x2 - x1, h = y2 - y1;
            float4 db = ((const float4*)dboxes)[d];
            float g0 = (cx - db.x) / (db.z * 0.1f);
            float g1 = (cy - db.y) / (db.w * 0.1f);
            float g2 = __logf(w / db.z) * 5.0f;
            float g3 = __logf(h / db.w) * 5.0f;
            float4 lp = ((const float4*)locs)[rowoff + d];
            float dd;
            dd = fabsf(lp.x - g0); acc += (dd < 1.0f) ? 0.5f * dd * dd : dd - 0.5f;
            dd = fabsf(lp.y - g1); acc += (dd < 1.0f) ? 0.5f * dd * dd : dd - 0.5f;
            dd = fabsf(lp.z - g2); acc += (dd < 1.0f) ? 0.5f * dd * dd : dd - 0.5f;
            dd = fabsf(lp.w - g3); acc += (dd < 1.0f) ? 0.5f * dd * dd : dd - 0.5f;
        }
    }
    sred[t] = acc; sredi[t] = cnt;
    __syncthreads();
    for (int s = 128; s > 0; s >>= 1) {
        if (t < s) { sred[t] += sred[t + s]; sredi[t] += sredi[t + s]; }
        __syncthreads();
    }
    if (t == 0) {
        if (sredi[0]) { atomicAdd(&n_pos[b], sredi[0]); atomicAdd(npt, sredi[0]); }
        if (sred[0] != 0.0) atomicAdd(loc_sum, sred[0]);
    }
}

// ---------------------------------------------------------------------------
// ce4: QUAD-per-row (C=81 fast path). 4 lanes own one row; each lane holds
// 21 elems in registers (5xfloat4 + tail). Quad reduce = 2 shfl_xor.
// logit[tgt] re-loaded from global (L1-hot). 16 rows per wave-iteration.
// ---------------------------------------------------------------------------
__global__ __launch_bounds__(256, 4)
void ce4_kernel(const float* __restrict__ cls, const int* __restrict__ tcls,
                float* __restrict__ negbuf, double* __restrict__ pos_sum,
                int R) {
    int lane = threadIdx.x & 63;
    int p = lane & 3;                       // position in quad
    int q = lane >> 2;                      // quad id in wave [0,16)
    int wid = (blockIdx.x * blockDim.x + threadIdx.x) >> 6;
    int nw  = (gridDim.x * blockDim.x) >> 6;
    double acc = 0.0;

    for (int base = wid * 16; base < R; base += nw * 16) {
        int row = base + q;
        bool valid = (row < R);
        const float* A = cls + (size_t)row * 81;

        float v[21];
        if (valid) {
#pragma unroll
            for (int k = 0; k < 5; ++k) {
                float4 f = *(const float4*)(A + k * 16 + p * 4);
                v[k * 4 + 0] = f.x; v[k * 4 + 1] = f.y;
                v[k * 4 + 2] = f.z; v[k * 4 + 3] = f.w;
            }
            v[20] = (p == 0) ? A[80] : -INFINITY;
        } else {
#pragma unroll
            for (int k = 0; k < 21; ++k) v[k] = 0.0f;   // dummy, result unused
        }

        // 3-way split max to shorten dependent chain
        float m0 = v[0], m1 = v[1], m2 = v[2];
#pragma unroll
        for (int k = 3; k < 21; k += 3) m0 = fmaxf(m0, v[k]);
#pragma unroll
        for (int k = 4; k < 21; k += 3) m1 = fmaxf(m1, v[k]);
#pragma unroll
        for (int k = 5; k < 21; k += 3) m2 = fmaxf(m2, v[k]);
        float m = fmaxf(fmaxf(m0, m1), m2);
        m = fmaxf(m, __shfl_xor(m, 1));
        m = fmaxf(m, __shfl_xor(m, 2));

        float e0 = 0.0f, e1 = 0.0f, e2 = 0.0f;
#pragma unroll
        for (int k = 0; k < 21; k += 3) e0 += __expf(v[k] - m);
#pragma unroll
        for (int k = 1; k < 21; k += 3) e1 += __expf(v[k] - m);
#pragma unroll
        for (int k = 2; k < 21; k += 3) e2 += __expf(v[k] - m);
        float e = e0 + e1 + e2;
        e += __shfl_xor(e, 1);
        e += __shfl_xor(e, 2);

        if (valid && p == 0) {
            int tgt = tcls[row];
            float lt = A[tgt];                          // L1-hot reload
            float ce = fmaxf(__logf(e) + m - lt, 0.0f);
            if (tgt != 0) { acc += (double)ce; negbuf[row] = 0.0f; }
            else          { negbuf[row] = ce; }
        }
    }

    // cross-quad reduce (non-leaders hold 0), one atomic per wave
#pragma unroll
    for (int s = 4; s < 64; s <<= 1) acc += __shfl_xor(acc, s);
    if (lane == 0 && acc != 0.0) atomicAdd(pos_sum, acc);
}

// ---------------------------------------------------------------------------
// ce2: fallback (general C <= 128): wave-per-row, 2 rows/iter
// ---------------------------------------------------------------------------
__global__ __launch_bounds__(256, 8)
void ce2_kernel(const float* __restrict__ cls, const int* __restrict__ tcls,
                float* __restrict__ negbuf, double* __restrict__ pos_sum,
                int R, int C) {
    int lane = threadIdx.x & 63;
    int wid  = (blockIdx.x * blockDim.x + threadIdx.x) >> 6;
    int nw   = (gridDim.x * blockDim.x) >> 6;
    double acc = 0.0;

    for (int r0 = wid * 2; r0 < R; r0 += nw * 2) {
        int r1 = r0 + 1;
        bool has1 = (r1 < R);
        const float* A  = cls + (size_t)r0 * C;
        const float* Bp = cls + (size_t)r1 * C;
        float a0 = (lane < C) ? A[lane] : -INFINITY;
        float a1 = (64 + lane < C) ? A[64 + lane] : -INFINITY;
        float b0 = (has1 && lane < C) ? Bp[lane] : -INFINITY;
        float b1 = (has1 && 64 + lane < C) ? Bp[64 + lane] : -INFINITY;
        int ta = tcls[r0];
        int tb = has1 ? tcls[r1] : 0;

        float ma = fmaxf(a0, a1), mb = fmaxf(b0, b1);
#pragma unroll
        for (int s = 32; s > 0; s >>= 1) {
            ma = fmaxf(ma, __shfl_xor(ma, s));
            mb = fmaxf(mb, __shfl_xor(mb, s));
        }
        float ea = __expf(a0 - ma) + __expf(a1 - ma);
        float eb = __expf(b0 - mb) + __expf(b1 - mb);
#pragma unroll
        for (int s = 32; s > 0; s >>= 1) {
            ea += __shfl_xor(ea, s);
            eb += __shfl_xor(eb, s);
        }
        int sa = (ta < 64) ? ta : ta - 64;
        int sb = (tb < 64) ? tb : tb - 64;
        float xa0 = __shfl(a0, sa), xa1 = __shfl(a1, sa);
        float xb0 = __shfl(b0, sb), xb1 = __shfl(b1, sb);
        float lta = (ta < 64) ? xa0 : xa1;
        float ltb = (tb < 64) ? xb0 : xb1;
        float cea = fmaxf(__logf(ea) + ma - lta, 0.0f);
        float ceb = fmaxf(__logf(eb) + mb - ltb, 0.0f);
        if (lane == 0) {
            if (ta != 0) { acc += (double)cea; negbuf[r0] = 0.0f; }
            else         { negbuf[r0] = cea; }
            if (has1) {
                if (tb != 0) { acc += (double)ceb; negbuf[r1] = 0.0f; }
                else         { negbuf[r1] = ceb; }
            }
        }
    }
    if (lane == 0 && acc != 0.0) atomicAdd(pos_sum, acc);
}

// ---------------------------------------------------------------------------
// hardneg (+ fused finalize): exact top-k sum via byte radix-select.
// 4 per-wave histogram replicas (count + value-sum); boundary via parallel
// 8-step suffix scan. Last block writes outputs.
// ---------------------------------------------------------------------------
__global__ __launch_bounds__(256) void hardneg_kernel(
        const float* __restrict__ neg, const int* __restrict__ n_pos,
        double* __restrict__ neg_sum, const int* __restrict__ npt,
        const double* __restrict__ loc_sum, const double* __restrict__ pos_sum,
        int* __restrict__ counter, float* __restrict__ out,
        int D, int uselds) {
    extern __shared__ float ldsrow[];
    int b = blockIdx.x, t = threadIdx.x;
    int w = t >> 6;
    const float* row = neg + (size_t)b * D;

    __shared__ unsigned bins[4][256];
    __shared__ float    fbins[4][256];
    __shared__ unsigned sc[2][256];
    __shared__ float    sf[2][256];
    __shared__ unsigned sh_kk, sh_prefix, sh_pmask;
    __shared__ double   sh_above;

    int k0 = 3 * n_pos[b];
    if (k0 > D) k0 = D;
    if (t == 0) { sh_kk = (unsigned)k0; sh_prefix = 0u; sh_pmask = 0u; sh_above = 0.0; }
    __syncthreads();

    if (k0 > 0) {
        for (int shift = 24; shift >= 0; shift -= 8) {
#pragma unroll
            for (int i = 0; i < 4; ++i) { bins[i][t] = 0; fbins[i][t] = 0.0f; }
            __syncthreads();
            unsigned pmask = sh_pmask, prefix = sh_prefix;
            unsigned kk = sh_kk;
            if (shift == 24) {
                for (int i = t; i < D; i += 256) {
                    float fv = row[i];
                    if (uselds) ldsrow[i] = fv;
                    unsigned v = __float_as_uint(fv);
                    atomicAdd(&bins[w][v >> 24], 1u);
                    atomicAdd(&fbins[w][v >> 24], fv);
                }
            } else {
                for (int i = t; i < D; i += 256) {
                    float fv = uselds ? ldsrow[i] : row[i];
                    unsigned v = __float_as_uint(fv);
                    if ((v & pmask) == prefix) {
                        atomicAdd(&bins[w][(v >> shift) & 255u], 1u);
                        atomicAdd(&fbins[w][(v >> shift) & 255u], fv);
                    }
                }
            }
            __syncthreads();
            sc[0][t] = bins[0][t] + bins[1][t] + bins[2][t] + bins[3][t];
            sf[0][t] = fbins[0][t] + fbins[1][t] + fbins[2][t] + fbins[3][t];
            __syncthreads();
            int src = 0;
#pragma unroll
            for (int off = 1; off < 256; off <<= 1) {
                int dst = 1 - src;
                unsigned cv = sc[src][t] + ((t + off < 256) ? sc[src][t + off] : 0u);
                float    fv = sf[src][t] + ((t + off < 256) ? sf[src][t + off] : 0.0f);
                sc[dst][t] = cv; sf[dst][t] = fv;
                __syncthreads();
                src = dst;
            }
            unsigned sufc  = sc[src][t];
            unsigned above = (t < 255) ? sc[src][t + 1] : 0u;
            if (sufc >= kk && above < kk) {
                sh_above += (double)((t < 255) ? sf[src][t + 1] : 0.0f);
                sh_kk = kk - above;
                sh_prefix = prefix | ((unsigned)t << shift);
                sh_pmask = pmask | (255u << shift);
            }
            __syncthreads();
        }
        if (t == 0) {
            double tot = sh_above +
                (double)sh_kk * (double)__uint_as_float(sh_prefix);
            if (tot != 0.0) atomicAdd(neg_sum, tot);
        }
    }

    __threadfence();
    if (t == 0) {
        int done = atomicAdd(counter, 1);
        if (done == (int)gridDim.x - 1) {
            double ls = atomicAdd((double*)loc_sum, 0.0);
            double ps = atomicAdd((double*)pos_sum, 0.0);
            double ns = atomicAdd(neg_sum, 0.0);
            int    n  = atomicAdd((int*)npt, 0);
            double nd = (double)n;
            out[0] = (float)(ls / (nd * 4.0));
            out[1] = (float)((ns + ps) / nd);
        }
    }
}

// ---------------------------------------------------------------------------
extern "C" void kernel_launch(void* const* d_in, const int* in_sizes, int n_in,
                              void* d_out, int out_size, void* d_ws, size_t ws_size,
                              hipStream_t stream) {
    const float* locs   = (const float*)d_in[0];
    const float* cls    = (const float*)d_in[1];
    const float* boxes  = (const float*)d_in[2];
    const int*   labels = (const int*)d_in[3];
    const float* dboxes = (const float*)d_in[4];

    int D = in_sizes[4] / 4;
    int B = in_sizes[0] / (4 * D);
    int O = in_sizes[3] / B;
    int C = in_sizes[1] / (B * D);
    int R = B * D;

    const int chunk = 1024;
    int CH1 = (D + chunk - 1) / chunk;
    int CHm = (D + 255) / 256;

    char* ws = (char*)d_ws;
    double* loc_sum = (double*)ws;                    // [0,8)
    double* pos_sum = loc_sum + 1;                    // [8,16)
    double* neg_sum = loc_sum + 2;                    // [16,24)
    int*    npt     = (int*)(ws + 24);                // [24,28)
    int*    counter = (int*)(ws + 28);                // [28,32)
    size_t off = 32;
    int* n_pos = (int*)(ws + off); off += (size_t)B * 4;
    off = (off + 7) & ~(size_t)7;
    unsigned long long* key64c = (unsigned long long*)(ws + off);
    off += (size_t)B * CH1 * O * 8;
    off = (off + 15) & ~(size_t)15;
    int*   tcls   = (int*)(ws + off); off += (size_t)R * 4;
    float* negbuf = (float*)(ws + off);

    m1_kernel<<<B * CH1, 256, 0, stream>>>(boxes, dboxes, tcls, negbuf /*ovl*/,
                                           key64c, n_pos, loc_sum, pos_sum, neg_sum,
                                           npt, counter, D, O, CH1, chunk);
    m3_kernel<<<B * CHm, 256, 0, stream>>>(boxes, labels, dboxes, locs, tcls, negbuf,
                                           key64c, n_pos, loc_sum, npt, D, O, CH1, CHm);
    if (C == 81 && (R % 16) == 0) {
        ce4_kernel<<<2048, 256, 0, stream>>>(cls, tcls, negbuf, pos_sum, R);
    } else {
        ce2_kernel<<<2048, 256, 0, stream>>>(cls, tcls, negbuf, pos_sum, R, C);
    }
    int uselds = (D * 4 <= 40000) ? 1 : 0;
    size_t shbytes = uselds ? (size_t)D * 4 : 0;
    hardneg_kernel<<<B, 256, shbytes, stream>>>(negbuf, n_pos, neg_sum, npt,
                                                loc_sum, pos_sum, counter,
                                                (float*)d_out, D, uselds);
}

// Round 8
// 188.494 us; speedup vs baseline: 1.5283x; 1.3304x over previous
//
#include <hip/hip_runtime.h>
#include <hip/hip_bf16.h>
#include <math.h>

#define MAXO 16
// fixed-point accumulators: value * 2^24 in a u64 (all summands >= 0)
#define FIXSCALE 16777216.0
__device__ __forceinline__ unsigned long long to_fix(double x) {
    return (unsigned long long)(x * FIXSCALE + 0.5);
}

// ---------------------------------------------------------------------------
// m1: IoU over (b, d-chunk). Per-default argmax over objects (first-wins) ->
//     tcls/ovl. Per-object argmax over defaults reduced block-locally, written
//     non-atomically to key64c[b][c][o]. Also inits scalar accumulators.
// ---------------------------------------------------------------------------
__global__ __launch_bounds__(256, 2)
void m1_kernel(const float* __restrict__ boxes,   // [B,O,4] xy
               const float* __restrict__ dboxes,  // [D,4] cxcy
               int*   __restrict__ tcls,          // [B,D] obj idx
               float* __restrict__ ovl,           // [B,D] best iou
               unsigned long long* __restrict__ key64c, // [B,CH,O]
               int*    __restrict__ n_pos,
               unsigned long long* __restrict__ loc_fix,
               unsigned long long* __restrict__ pos_fix,
               unsigned long long* __restrict__ neg_fix,
               int*    __restrict__ npt,
               int*    __restrict__ counter,
               int D, int O, int CH, int chunk) {
    int b = blockIdx.x / CH, c = blockIdx.x % CH;
    int t = threadIdx.x;

    if (c == 0) {
        if (t == 0) n_pos[b] = 0;
        if (b == 0) {
            if (t == 1) *loc_fix = 0ull;
            if (t == 2) *pos_fix = 0ull;
            if (t == 3) *neg_fix = 0ull;
            if (t == 4) *npt = 0;
            if (t == 5) *counter = 0;
        }
    }

    __shared__ float sbox[MAXO][4];
    __shared__ float sarea[MAXO];
    __shared__ unsigned long long skey[4][MAXO];
    if (t < O) {
        const float* bp = boxes + ((size_t)b * O + t) * 4;
        float x1 = bp[0], y1 = bp[1], x2 = bp[2], y2 = bp[3];
        sbox[t][0] = x1; sbox[t][1] = y1; sbox[t][2] = x2; sbox[t][3] = y2;
        sarea[t] = (x2 - x1) * (y2 - y1);
    }
    __syncthreads();

    unsigned long long bestk[MAXO];
#pragma unroll
    for (int o = 0; o < MAXO; ++o) bestk[o] = 0ull;

    size_t rowoff = (size_t)b * D;
    int d0 = c * chunk, d1 = min(D, d0 + chunk);

    for (int d = d0 + t; d < d1; d += 256) {
        float4 db = ((const float4*)dboxes)[d];
        float dx1 = db.x - db.z * 0.5f, dy1 = db.y - db.w * 0.5f;
        float dx2 = db.x + db.z * 0.5f, dy2 = db.y + db.w * 0.5f;
        float a2 = (dx2 - dx1) * (dy2 - dy1);
        unsigned notd = 0xFFFFFFFFu - (unsigned)d;
        float mval = -1.0f; int mobj = 0;
#pragma unroll
        for (int o = 0; o < MAXO; ++o) {
            if (o < O) {
                float lx = fmaxf(sbox[o][0], dx1), ly = fmaxf(sbox[o][1], dy1);
                float rx = fminf(sbox[o][2], dx2), ry = fminf(sbox[o][3], dy2);
                float w = fmaxf(rx - lx, 0.0f), h = fmaxf(ry - ly, 0.0f);
                float inter = w * h;
                float iou = inter / (sarea[o] + a2 - inter);
                if (iou > mval) { mval = iou; mobj = o; }   // first-wins over o
                unsigned long long key =
                    ((unsigned long long)__float_as_uint(iou) << 32) |
                    (unsigned long long)notd;               // max iou, lowest d
                if (key > bestk[o]) bestk[o] = key;
            }
        }
        tcls[rowoff + d] = mobj;
        ovl[rowoff + d]  = mval;
    }

    int w = t >> 6;
#pragma unroll
    for (int o = 0; o < MAXO; ++o) {
        if (o < O) {
            unsigned long long k = bestk[o];
            for (int s = 32; s > 0; s >>= 1) {
                unsigned long long k2 =
                    (unsigned long long)__shfl_xor((long long)k, s);
                if (k2 > k) k = k2;
            }
            if ((t & 63) == 0) skey[w][o] = k;
        }
    }
    __syncthreads();
    if (t < O) {
        unsigned long long k = skey[0][t];
#pragma unroll
        for (int i = 1; i < 4; ++i) {
            unsigned long long k2 = skey[i][t];
            if (k2 > k) k = k2;
        }
        key64c[((size_t)b * CH + c) * O + t] = k;
    }
}

// ---------------------------------------------------------------------------
// m3: chunk-key reduce inline, labels (override inline, ascending = last-wins),
//     encode + smooth-L1; n_pos / npt (int atomics) / loc_fix (u64 atomic)
// ---------------------------------------------------------------------------
__global__ void m3_kernel(const float* __restrict__ boxes,
                          const int*   __restrict__ labels,
                          const float* __restrict__ dboxes,
                          const float* __restrict__ locs,
                          int*   __restrict__ tcls,
                          const float* __restrict__ ovl,
                          const unsigned long long* __restrict__ key64c, // [B,CH,O]
                          int*   __restrict__ n_pos,
                          unsigned long long* __restrict__ loc_fix,
                          int*   __restrict__ npt,
                          int D, int O, int CH, int CHm) {
    int b = blockIdx.x / CHm, c = blockIdx.x % CHm;
    int t = threadIdx.x;
    int d = c * 256 + t;

    __shared__ float sbox[MAXO][4];
    __shared__ int   slab[MAXO];
    __shared__ int   sdstar[MAXO];
    __shared__ double sred[256];
    __shared__ int    sredi[256];
    if (t < O) {
        const float* bp = boxes + ((size_t)b * O + t) * 4;
        sbox[t][0] = bp[0]; sbox[t][1] = bp[1]; sbox[t][2] = bp[2]; sbox[t][3] = bp[3];
        slab[t] = labels[(size_t)b * O + t];
        unsigned long long k = 0ull;
        for (int cc = 0; cc < CH; ++cc) {
            unsigned long long k2 = key64c[((size_t)b * CH + cc) * O + t];
            if (k2 > k) k = k2;
        }
        sdstar[t] = (int)(0xFFFFFFFFu - (unsigned)(k & 0xFFFFFFFFull));
    }
    __syncthreads();

    double acc = 0.0;
    int cnt = 0;
    if (d < D) {
        size_t rowoff = (size_t)b * D;
        int o = tcls[rowoff + d];
        float ov = ovl[rowoff + d];
#pragma unroll
        for (int oo = 0; oo < MAXO; ++oo) {        // ascending -> last-write-wins
            if (oo < O && sdstar[oo] == d) { o = oo; ov = 1.0f; }
        }
        int lab = (ov < 0.5f) ? 0 : slab[o];
        tcls[rowoff + d] = lab;
        if (lab != 0) {
            cnt = 1;
            float x1 = sbox[o][0], y1 = sbox[o][1], x2 = sbox[o][2], y2 = sbox[o][3];
            float cx = (x1 + x2) * 0.5f, cy = (y1 + y2) * 0.5f;
            float w = x2 - x1, h = y2 - y1;
            float4 db = ((const float4*)dboxes)[d];
            float g0 = (cx - db.x) / (db.z * 0.1f);
            float g1 = (cy - db.y) / (db.w * 0.1f);
            float g2 = __logf(w / db.z) * 5.0f;
            float g3 = __logf(h / db.w) * 5.0f;
            float4 lp = ((const float4*)locs)[rowoff + d];
            float dd;
            dd = fabsf(lp.x - g0); acc += (dd < 1.0f) ? 0.5f * dd * dd : dd - 0.5f;
            dd = fabsf(lp.y - g1); acc += (dd < 1.0f) ? 0.5f * dd * dd : dd - 0.5f;
            dd = fabsf(lp.z - g2); acc += (dd < 1.0f) ? 0.5f * dd * dd : dd - 0.5f;
            dd = fabsf(lp.w - g3); acc += (dd < 1.0f) ? 0.5f * dd * dd : dd - 0.5f;
        }
    }
    sred[t] = acc; sredi[t] = cnt;
    __syncthreads();
    for (int s = 128; s > 0; s >>= 1) {
        if (t < s) { sred[t] += sred[t + s]; sredi[t] += sredi[t + s]; }
        __syncthreads();
    }
    if (t == 0) {
        if (sredi[0]) { atomicAdd(&n_pos[b], sredi[0]); atomicAdd(npt, sredi[0]); }
        if (sred[0] != 0.0) atomicAdd(loc_fix, to_fix(sred[0]));
    }
}

// ---------------------------------------------------------------------------
// ce4: QUAD-per-row (C=81). Per-wave shfl reduce -> per-block LDS reduce ->
//      ONE u64 fixed-point atomic per block (was: per-wave f64 CAS-loop).
// ---------------------------------------------------------------------------
__global__ __launch_bounds__(256, 4)
void ce4_kernel(const float* __restrict__ cls, const int* __restrict__ tcls,
                float* __restrict__ negbuf, unsigned long long* __restrict__ pos_fix,
                int R) {
    int lane = threadIdx.x & 63;
    int p = lane & 3;
    int q = lane >> 2;
    int wid = (blockIdx.x * blockDim.x + threadIdx.x) >> 6;
    int nw  = (gridDim.x * blockDim.x) >> 6;
    double acc = 0.0;

    for (int base = wid * 16; base < R; base += nw * 16) {
        int row = base + q;
        bool valid = (row < R);
        const float* A = cls + (size_t)row * 81;

        float v[21];
        if (valid) {
#pragma unroll
            for (int k = 0; k < 5; ++k) {
                float4 f = *(const float4*)(A + k * 16 + p * 4);
                v[k * 4 + 0] = f.x; v[k * 4 + 1] = f.y;
                v[k * 4 + 2] = f.z; v[k * 4 + 3] = f.w;
            }
            v[20] = (p == 0) ? A[80] : -INFINITY;
        } else {
#pragma unroll
            for (int k = 0; k < 21; ++k) v[k] = 0.0f;
        }

        float m0 = v[0], m1 = v[1], m2 = v[2];
#pragma unroll
        for (int k = 3; k < 21; k += 3) m0 = fmaxf(m0, v[k]);
#pragma unroll
        for (int k = 4; k < 21; k += 3) m1 = fmaxf(m1, v[k]);
#pragma unroll
        for (int k = 5; k < 21; k += 3) m2 = fmaxf(m2, v[k]);
        float m = fmaxf(fmaxf(m0, m1), m2);
        m = fmaxf(m, __shfl_xor(m, 1));
        m = fmaxf(m, __shfl_xor(m, 2));

        float e0 = 0.0f, e1 = 0.0f, e2 = 0.0f;
#pragma unroll
        for (int k = 0; k < 21; k += 3) e0 += __expf(v[k] - m);
#pragma unroll
        for (int k = 1; k < 21; k += 3) e1 += __expf(v[k] - m);
#pragma unroll
        for (int k = 2; k < 21; k += 3) e2 += __expf(v[k] - m);
        float e = e0 + e1 + e2;
        e += __shfl_xor(e, 1);
        e += __shfl_xor(e, 2);

        if (valid && p == 0) {
            int tgt = tcls[row];
            float lt = A[tgt];
            float ce = fmaxf(__logf(e) + m - lt, 0.0f);
            if (tgt != 0) { acc += (double)ce; negbuf[row] = 0.0f; }
            else          { negbuf[row] = ce; }
        }
    }

    // wave reduce (leaders at lane%4==0 hold partials)
#pragma unroll
    for (int s = 4; s < 64; s <<= 1) acc += __shfl_xor(acc, s);
    // block reduce -> one integer atomic
    __shared__ double swacc[4];
    if (lane == 0) swacc[threadIdx.x >> 6] = acc;
    __syncthreads();
    if (threadIdx.x == 0) {
        double s = swacc[0] + swacc[1] + swacc[2] + swacc[3];
        if (s != 0.0) atomicAdd(pos_fix, to_fix(s));
    }
}

// ---------------------------------------------------------------------------
// ce2: fallback (general C <= 128): wave-per-row, 2 rows/iter
// ---------------------------------------------------------------------------
__global__ __launch_bounds__(256, 8)
void ce2_kernel(const float* __restrict__ cls, const int* __restrict__ tcls,
                float* __restrict__ negbuf, unsigned long long* __restrict__ pos_fix,
                int R, int C) {
    int lane = threadIdx.x & 63;
    int wid  = (blockIdx.x * blockDim.x + threadIdx.x) >> 6;
    int nw   = (gridDim.x * blockDim.x) >> 6;
    double acc = 0.0;

    for (int r0 = wid * 2; r0 < R; r0 += nw * 2) {
        int r1 = r0 + 1;
        bool has1 = (r1 < R);
        const float* A  = cls + (size_t)r0 * C;
        const float* Bp = cls + (size_t)r1 * C;
        float a0 = (lane < C) ? A[lane] : -INFINITY;
        float a1 = (64 + lane < C) ? A[64 + lane] : -INFINITY;
        float b0 = (has1 && lane < C) ? Bp[lane] : -INFINITY;
        float b1 = (has1 && 64 + lane < C) ? Bp[64 + lane] : -INFINITY;
        int ta = tcls[r0];
        int tb = has1 ? tcls[r1] : 0;

        float ma = fmaxf(a0, a1), mb = fmaxf(b0, b1);
#pragma unroll
        for (int s = 32; s > 0; s >>= 1) {
            ma = fmaxf(ma, __shfl_xor(ma, s));
            mb = fmaxf(mb, __shfl_xor(mb, s));
        }
        float ea = __expf(a0 - ma) + __expf(a1 - ma);
        float eb = __expf(b0 - mb) + __expf(b1 - mb);
#pragma unroll
        for (int s = 32; s > 0; s >>= 1) {
            ea += __shfl_xor(ea, s);
            eb += __shfl_xor(eb, s);
        }
        int sa = (ta < 64) ? ta : ta - 64;
        int sb = (tb < 64) ? tb : tb - 64;
        float xa0 = __shfl(a0, sa), xa1 = __shfl(a1, sa);
        float xb0 = __shfl(b0, sb), xb1 = __shfl(b1, sb);
        float lta = (ta < 64) ? xa0 : xa1;
        float ltb = (tb < 64) ? xb0 : xb1;
        float cea = fmaxf(__logf(ea) + ma - lta, 0.0f);
        float ceb = fmaxf(__logf(eb) + mb - ltb, 0.0f);
        if (lane == 0) {
            if (ta != 0) { acc += (double)cea; negbuf[r0] = 0.0f; }
            else         { negbuf[r0] = cea; }
            if (has1) {
                if (tb != 0) { acc += (double)ceb; negbuf[r1] = 0.0f; }
                else         { negbuf[r1] = ceb; }
            }
        }
    }
    __shared__ double swacc[4];
    if (lane == 0) swacc[threadIdx.x >> 6] = acc;
    __syncthreads();
    if (threadIdx.x == 0) {
        double s = swacc[0] + swacc[1] + swacc[2] + swacc[3];
        if (s != 0.0) atomicAdd(pos_fix, to_fix(s));
    }
}

// ---------------------------------------------------------------------------
// hardneg (+ fused finalize): exact top-k sum via byte radix-select.
// 4 per-wave histogram replicas; parallel suffix scan; u64 fixed-point atomic.
// ---------------------------------------------------------------------------
__global__ __launch_bounds__(256) void hardneg_kernel(
        const float* __restrict__ neg, const int* __restrict__ n_pos,
        unsigned long long* __restrict__ neg_fix, const int* __restrict__ npt,
        const unsigned long long* __restrict__ loc_fix,
        const unsigned long long* __restrict__ pos_fix,
        int* __restrict__ counter, float* __restrict__ out,
        int D, int uselds) {
    extern __shared__ float ldsrow[];
    int b = blockIdx.x, t = threadIdx.x;
    int w = t >> 6;
    const float* row = neg + (size_t)b * D;

    __shared__ unsigned bins[4][256];
    __shared__ float    fbins[4][256];
    __shared__ unsigned sc[2][256];
    __shared__ float    sf[2][256];
    __shared__ unsigned sh_kk, sh_prefix, sh_pmask;
    __shared__ double   sh_above;

    int k0 = 3 * n_pos[b];
    if (k0 > D) k0 = D;
    if (t == 0) { sh_kk = (unsigned)k0; sh_prefix = 0u; sh_pmask = 0u; sh_above = 0.0; }
    __syncthreads();

    if (k0 > 0) {
        for (int shift = 24; shift >= 0; shift -= 8) {
#pragma unroll
            for (int i = 0; i < 4; ++i) { bins[i][t] = 0; fbins[i][t] = 0.0f; }
            __syncthreads();
            unsigned pmask = sh_pmask, prefix = sh_prefix;
            unsigned kk = sh_kk;
            if (shift == 24) {
                for (int i = t; i < D; i += 256) {
                    float fv = row[i];
                    if (uselds) ldsrow[i] = fv;
                    unsigned v = __float_as_uint(fv);
                    atomicAdd(&bins[w][v >> 24], 1u);
                    atomicAdd(&fbins[w][v >> 24], fv);
                }
            } else {
                for (int i = t; i < D; i += 256) {
                    float fv = uselds ? ldsrow[i] : row[i];
                    unsigned v = __float_as_uint(fv);
                    if ((v & pmask) == prefix) {
                        atomicAdd(&bins[w][(v >> shift) & 255u], 1u);
                        atomicAdd(&fbins[w][(v >> shift) & 255u], fv);
                    }
                }
            }
            __syncthreads();
            sc[0][t] = bins[0][t] + bins[1][t] + bins[2][t] + bins[3][t];
            sf[0][t] = fbins[0][t] + fbins[1][t] + fbins[2][t] + fbins[3][t];
            __syncthreads();
            int src = 0;
#pragma unroll
            for (int off = 1; off < 256; off <<= 1) {
                int dst = 1 - src;
                unsigned cv = sc[src][t] + ((t + off < 256) ? sc[src][t + off] : 0u);
                float    fv = sf[src][t] + ((t + off < 256) ? sf[src][t + off] : 0.0f);
                sc[dst][t] = cv; sf[dst][t] = fv;
                __syncthreads();
                src = dst;
            }
            unsigned sufc  = sc[src][t];
            unsigned above = (t < 255) ? sc[src][t + 1] : 0u;
            if (sufc >= kk && above < kk) {
                sh_above += (double)((t < 255) ? sf[src][t + 1] : 0.0f);
                sh_kk = kk - above;
                sh_prefix = prefix | ((unsigned)t << shift);
                sh_pmask = pmask | (255u << shift);
            }
            __syncthreads();
        }
        if (t == 0) {
            double tot = sh_above +
                (double)sh_kk * (double)__uint_as_float(sh_prefix);
            if (tot != 0.0) atomicAdd(neg_fix, to_fix(tot));
        }
    }

    __threadfence();
    if (t == 0) {
        int done = atomicAdd(counter, 1);
        if (done == (int)gridDim.x - 1) {
            double ls = (double)atomicAdd((unsigned long long*)loc_fix, 0ull) / FIXSCALE;
            double ps = (double)atomicAdd((unsigned long long*)pos_fix, 0ull) / FIXSCALE;
            double ns = (double)atomicAdd(neg_fix, 0ull) / FIXSCALE;
            int    n  = atomicAdd((int*)npt, 0);
            double nd = (double)n;
            out[0] = (float)(ls / (nd * 4.0));
            out[1] = (float)((ns + ps) / nd);
        }
    }
}

// ---------------------------------------------------------------------------
extern "C" void kernel_launch(void* const* d_in, const int* in_sizes, int n_in,
                              void* d_out, int out_size, void* d_ws, size_t ws_size,
                              hipStream_t stream) {
    const float* locs   = (const float*)d_in[0];
    const float* cls    = (const float*)d_in[1];
    const float* boxes  = (const float*)d_in[2];
    const int*   labels = (const int*)d_in[3];
    const float* dboxes = (const float*)d_in[4];

    int D = in_sizes[4] / 4;
    int B = in_sizes[0] / (4 * D);
    int O = in_sizes[3] / B;
    int C = in_sizes[1] / (B * D);
    int R = B * D;

    const int chunk = 1024;
    int CH1 = (D + chunk - 1) / chunk;
    int CHm = (D + 255) / 256;

    char* ws = (char*)d_ws;
    unsigned long long* loc_fix = (unsigned long long*)ws;        // [0,8)
    unsigned long long* pos_fix = loc_fix + 1;                    // [8,16)
    unsigned long long* neg_fix = loc_fix + 2;                    // [16,24)
    int*    npt     = (int*)(ws + 24);                            // [24,28)
    int*    counter = (int*)(ws + 28);                            // [28,32)
    size_t off = 32;
    int* n_pos = (int*)(ws + off); off += (size_t)B * 4;
    off = (off + 7) & ~(size_t)7;
    unsigned long long* key64c = (unsigned long long*)(ws + off);
    off += (size_t)B * CH1 * O * 8;
    off = (off + 15) & ~(size_t)15;
    int*   tcls   = (int*)(ws + off); off += (size_t)R * 4;
    float* negbuf = (float*)(ws + off);

    m1_kernel<<<B * CH1, 256, 0, stream>>>(boxes, dboxes, tcls, negbuf /*ovl*/,
                                           key64c, n_pos, loc_fix, pos_fix, neg_fix,
                                           npt, counter, D, O, CH1, chunk);
    m3_kernel<<<B * CHm, 256, 0, stream>>>(boxes, labels, dboxes, locs, tcls, negbuf,
                                           key64c, n_pos, loc_fix, npt, D, O, CH1, CHm);
    if (C == 81 && (R % 16) == 0) {
        ce4_kernel<<<2048, 256, 0, stream>>>(cls, tcls, negbuf, pos_fix, R);
    } else {
        ce2_kernel<<<2048, 256, 0, stream>>>(cls, tcls, negbuf, pos_fix, R, C);
    }
    int uselds = (D * 4 <= 40000) ? 1 : 0;
    size_t shbytes = uselds ? (size_t)D * 4 : 0;
    hardneg_kernel<<<B, 256, shbytes, stream>>>(negbuf, n_pos, neg_fix, npt,
                                                loc_fix, pos_fix, counter,
                                                (float*)d_out, D, uselds);
}

// Round 9
// 168.221 us; speedup vs baseline: 1.7125x; 1.1205x over previous
//
#include <hip/hip_runtime.h>
#include <hip/hip_bf16.h>
#include <math.h>

#define MAXO 16

// ---------------------------------------------------------------------------
// match_kernel: one block per batch. Phase 1: IoU, per-default argmax over
// objects (first-wins) -> LDS, per-object argmax over defaults (max iou,
// lowest d) in registers -> block reduce -> LDS. Phase 2: override (ascending
// scan = last-write-wins), labels -> tcls (global), encode + smooth-L1 ->
// plain per-batch partials (no atomics anywhere).
// ---------------------------------------------------------------------------
__global__ __launch_bounds__(256, 2)
void match_kernel(const float* __restrict__ boxes,   // [B,O,4] xy
                  const int*   __restrict__ labels,  // [B,O]
                  const float* __restrict__ dboxes,  // [D,4] cxcy
                  const float* __restrict__ locs,    // [B,D,4]
                  int*    __restrict__ tcls,         // [B,D] label out
                  int*    __restrict__ n_pos,        // [B]
                  double* __restrict__ locpart,      // [B]
                  int D, int O) {
    int b = blockIdx.x;
    int t = threadIdx.x;

    extern __shared__ __align__(16) char smem[];
    float*         sOvl = (float*)smem;            // D floats
    unsigned char* sObj = (unsigned char*)(smem + (size_t)D * 4); // D bytes

    __shared__ float sbox[MAXO][4];
    __shared__ float sarea[MAXO];
    __shared__ int   slab[MAXO];
    __shared__ unsigned long long skey[4][MAXO];
    __shared__ int   sdstar[MAXO];
    __shared__ double sred[256];
    __shared__ int    sredi[256];

    if (t < O) {
        const float* bp = boxes + ((size_t)b * O + t) * 4;
        float x1 = bp[0], y1 = bp[1], x2 = bp[2], y2 = bp[3];
        sbox[t][0] = x1; sbox[t][1] = y1; sbox[t][2] = x2; sbox[t][3] = y2;
        sarea[t] = (x2 - x1) * (y2 - y1);
        slab[t]  = labels[(size_t)b * O + t];
    }
    __syncthreads();

    unsigned long long bestk[MAXO];
#pragma unroll
    for (int o = 0; o < MAXO; ++o) bestk[o] = 0ull;

    // ---- phase 1: IoU ----
    for (int d = t; d < D; d += 256) {
        float4 db = ((const float4*)dboxes)[d];
        float dx1 = db.x - db.z * 0.5f, dy1 = db.y - db.w * 0.5f;
        float dx2 = db.x + db.z * 0.5f, dy2 = db.y + db.w * 0.5f;
        float a2 = (dx2 - dx1) * (dy2 - dy1);
        unsigned notd = 0xFFFFFFFFu - (unsigned)d;
        float mval = -1.0f; int mobj = 0;
#pragma unroll
        for (int o = 0; o < MAXO; ++o) {
            if (o < O) {
                float lx = fmaxf(sbox[o][0], dx1), ly = fmaxf(sbox[o][1], dy1);
                float rx = fminf(sbox[o][2], dx2), ry = fminf(sbox[o][3], dy2);
                float w = fmaxf(rx - lx, 0.0f), h = fmaxf(ry - ly, 0.0f);
                float inter = w * h;
                float iou = inter / (sarea[o] + a2 - inter);
                if (iou > mval) { mval = iou; mobj = o; }   // first-wins over o
                unsigned long long key =
                    ((unsigned long long)__float_as_uint(iou) << 32) |
                    (unsigned long long)notd;               // max iou, lowest d
                if (key > bestk[o]) bestk[o] = key;
            }
        }
        sObj[d] = (unsigned char)mobj;
        sOvl[d] = mval;
    }

    // per-object argmax: wave shfl -> cross-wave LDS -> sdstar
    int w = t >> 6;
#pragma unroll
    for (int o = 0; o < MAXO; ++o) {
        if (o < O) {
            unsigned long long k = bestk[o];
            for (int s = 32; s > 0; s >>= 1) {
                unsigned long long k2 =
                    (unsigned long long)__shfl_xor((long long)k, s);
                if (k2 > k) k = k2;
            }
            if ((t & 63) == 0) skey[w][o] = k;
        }
    }
    __syncthreads();
    if (t < O) {
        unsigned long long k = skey[0][t];
#pragma unroll
        for (int i = 1; i < 4; ++i) {
            unsigned long long k2 = skey[i][t];
            if (k2 > k) k = k2;
        }
        sdstar[t] = (int)(0xFFFFFFFFu - (unsigned)(k & 0xFFFFFFFFull));
    }
    __syncthreads();

    // ---- phase 2: labels + loc loss ----
    double acc = 0.0;
    int cnt = 0;
    size_t rowoff = (size_t)b * D;
    for (int d = t; d < D; d += 256) {
        int o = sObj[d];
        float ov = sOvl[d];
#pragma unroll
        for (int oo = 0; oo < MAXO; ++oo) {        // ascending -> last-wins
            if (oo < O && sdstar[oo] == d) { o = oo; ov = 1.0f; }
        }
        int lab = (ov < 0.5f) ? 0 : slab[o];
        tcls[rowoff + d] = lab;
        if (lab != 0) {
            cnt++;
            float x1 = sbox[o][0], y1 = sbox[o][1], x2 = sbox[o][2], y2 = sbox[o][3];
            float cx = (x1 + x2) * 0.5f, cy = (y1 + y2) * 0.5f;
            float w2 = x2 - x1, h2 = y2 - y1;
            float4 db = ((const float4*)dboxes)[d];
            float g0 = (cx - db.x) / (db.z * 0.1f);
            float g1 = (cy - db.y) / (db.w * 0.1f);
            float g2 = __logf(w2 / db.z) * 5.0f;
            float g3 = __logf(h2 / db.w) * 5.0f;
            float4 lp = ((const float4*)locs)[rowoff + d];
            float dd;
            dd = fabsf(lp.x - g0); acc += (dd < 1.0f) ? 0.5f * dd * dd : dd - 0.5f;
            dd = fabsf(lp.y - g1); acc += (dd < 1.0f) ? 0.5f * dd * dd : dd - 0.5f;
            dd = fabsf(lp.z - g2); acc += (dd < 1.0f) ? 0.5f * dd * dd : dd - 0.5f;
            dd = fabsf(lp.w - g3); acc += (dd < 1.0f) ? 0.5f * dd * dd : dd - 0.5f;
        }
    }
    sred[t] = acc; sredi[t] = cnt;
    __syncthreads();
    for (int s = 128; s > 0; s >>= 1) {
        if (t < s) { sred[t] += sred[t + s]; sredi[t] += sredi[t + s]; }
        __syncthreads();
    }
    if (t == 0) {
        n_pos[b]   = sredi[0];   // plain stores, no atomics
        locpart[b] = sred[0];
    }
}

// ---------------------------------------------------------------------------
// ce4: QUAD-per-row, C=81. Row held in NAMED float4 registers (no array ->
// no regalloc reload-from-global). One plain partial store per block.
// ---------------------------------------------------------------------------
__global__ __launch_bounds__(256, 4)
void ce4_kernel(const float* __restrict__ cls, const int* __restrict__ tcls,
                float* __restrict__ negbuf, double* __restrict__ pospart,
                int R) {
    int lane = threadIdx.x & 63;
    int p = lane & 3;
    int q = lane >> 2;
    int wid = (blockIdx.x * blockDim.x + threadIdx.x) >> 6;
    int nw  = (gridDim.x * blockDim.x) >> 6;
    double acc = 0.0;

    for (int base = wid * 16; base < R; base += nw * 16) {
        int row = base + q;
        const float* Ar = cls + (size_t)row * 81;
        const float* A  = Ar + p * 4;
        float4 f0 = *(const float4*)(A);
        float4 f1 = *(const float4*)(A + 16);
        float4 f2 = *(const float4*)(A + 32);
        float4 f3 = *(const float4*)(A + 48);
        float4 f4 = *(const float4*)(A + 64);
        float t80 = Ar[80];     // quad-uniform; idempotent in max, gated in sum

        float ma = fmaxf(fmaxf(f0.x, f0.y), fmaxf(f0.z, f0.w));
        float mb = fmaxf(fmaxf(f1.x, f1.y), fmaxf(f1.z, f1.w));
        float mc = fmaxf(fmaxf(f2.x, f2.y), fmaxf(f2.z, f2.w));
        float md = fmaxf(fmaxf(f3.x, f3.y), fmaxf(f3.z, f3.w));
        float me = fmaxf(fmaxf(f4.x, f4.y), fmaxf(f4.z, f4.w));
        float m = fmaxf(fmaxf(fmaxf(ma, mb), fmaxf(mc, md)), fmaxf(me, t80));
        m = fmaxf(m, __shfl_xor(m, 1));
        m = fmaxf(m, __shfl_xor(m, 2));

        float e = __expf(f0.x - m) + __expf(f0.y - m) + __expf(f0.z - m) + __expf(f0.w - m)
                + __expf(f1.x - m) + __expf(f1.y - m) + __expf(f1.z - m) + __expf(f1.w - m)
                + __expf(f2.x - m) + __expf(f2.y - m) + __expf(f2.z - m) + __expf(f2.w - m)
                + __expf(f3.x - m) + __expf(f3.y - m) + __expf(f3.z - m) + __expf(f3.w - m)
                + __expf(f4.x - m) + __expf(f4.y - m) + __expf(f4.z - m) + __expf(f4.w - m);
        if (p == 0) e += __expf(t80 - m);
        e += __shfl_xor(e, 1);
        e += __shfl_xor(e, 2);

        if (p == 0) {
            int tgt = tcls[row];
            float lt = Ar[tgt];                     // L1-hot reload
            float ce = fmaxf(__logf(e) + m - lt, 0.0f);
            if (tgt != 0) { acc += (double)ce; negbuf[row] = 0.0f; }
            else          { negbuf[row] = ce; }
        }
    }

    // wave reduce (partials live on lanes with p==0)
#pragma unroll
    for (int s = 4; s < 64; s <<= 1) acc += __shfl_xor(acc, s);
    __shared__ double swacc[4];
    if (lane == 0) swacc[threadIdx.x >> 6] = acc;
    __syncthreads();
    if (threadIdx.x == 0)
        pospart[blockIdx.x] = swacc[0] + swacc[1] + swacc[2] + swacc[3];
}

// ---------------------------------------------------------------------------
// ce2: fallback (general C <= 128): wave-per-row, 2 rows/iter
// ---------------------------------------------------------------------------
__global__ __launch_bounds__(256, 8)
void ce2_kernel(const float* __restrict__ cls, const int* __restrict__ tcls,
                float* __restrict__ negbuf, double* __restrict__ pospart,
                int R, int C) {
    int lane = threadIdx.x & 63;
    int wid  = (blockIdx.x * blockDim.x + threadIdx.x) >> 6;
    int nw   = (gridDim.x * blockDim.x) >> 6;
    double acc = 0.0;

    for (int r0 = wid * 2; r0 < R; r0 += nw * 2) {
        int r1 = r0 + 1;
        bool has1 = (r1 < R);
        const float* A  = cls + (size_t)r0 * C;
        const float* Bp = cls + (size_t)r1 * C;
        float a0 = (lane < C) ? A[lane] : -INFINITY;
        float a1 = (64 + lane < C) ? A[64 + lane] : -INFINITY;
        float b0 = (has1 && lane < C) ? Bp[lane] : -INFINITY;
        float b1 = (has1 && 64 + lane < C) ? Bp[64 + lane] : -INFINITY;
        int ta = tcls[r0];
        int tb = has1 ? tcls[r1] : 0;

        float ma = fmaxf(a0, a1), mb = fmaxf(b0, b1);
#pragma unroll
        for (int s = 32; s > 0; s >>= 1) {
            ma = fmaxf(ma, __shfl_xor(ma, s));
            mb = fmaxf(mb, __shfl_xor(mb, s));
        }
        float ea = __expf(a0 - ma) + __expf(a1 - ma);
        float eb = __expf(b0 - mb) + __expf(b1 - mb);
#pragma unroll
        for (int s = 32; s > 0; s >>= 1) {
            ea += __shfl_xor(ea, s);
            eb += __shfl_xor(eb, s);
        }
        int sa = (ta < 64) ? ta : ta - 64;
        int sb = (tb < 64) ? tb : tb - 64;
        float xa0 = __shfl(a0, sa), xa1 = __shfl(a1, sa);
        float xb0 = __shfl(b0, sb), xb1 = __shfl(b1, sb);
        float lta = (ta < 64) ? xa0 : xa1;
        float ltb = (tb < 64) ? xb0 : xb1;
        float cea = fmaxf(__logf(ea) + ma - lta, 0.0f);
        float ceb = fmaxf(__logf(eb) + mb - ltb, 0.0f);
        if (lane == 0) {
            if (ta != 0) { acc += (double)cea; negbuf[r0] = 0.0f; }
            else         { negbuf[r0] = cea; }
            if (has1) {
                if (tb != 0) { acc += (double)ceb; negbuf[r1] = 0.0f; }
                else         { negbuf[r1] = ceb; }
            }
        }
    }
    __shared__ double swacc[4];
    if (lane == 0) swacc[threadIdx.x >> 6] = acc;
    __syncthreads();
    if (threadIdx.x == 0)
        pospart[blockIdx.x] = swacc[0] + swacc[1] + swacc[2] + swacc[3];
}

// ---------------------------------------------------------------------------
// hardneg: exact top-k sum via byte radix-select; 4 per-wave histogram
// replicas; parallel suffix scan. Plain per-batch partial store.
// ---------------------------------------------------------------------------
__global__ __launch_bounds__(256) void hardneg_kernel(
        const float* __restrict__ neg, const int* __restrict__ n_pos,
        double* __restrict__ negpart, int D, int uselds) {
    extern __shared__ float ldsrow[];
    int b = blockIdx.x, t = threadIdx.x;
    int w = t >> 6;
    const float* row = neg + (size_t)b * D;

    __shared__ unsigned bins[4][256];
    __shared__ float    fbins[4][256];
    __shared__ unsigned sc[2][256];
    __shared__ float    sf[2][256];
    __shared__ unsigned sh_kk, sh_prefix, sh_pmask;
    __shared__ double   sh_above;

    int k0 = 3 * n_pos[b];
    if (k0 > D) k0 = D;
    if (t == 0) { sh_kk = (unsigned)k0; sh_prefix = 0u; sh_pmask = 0u; sh_above = 0.0; }
    __syncthreads();

    double tot = 0.0;
    if (k0 > 0) {
        for (int shift = 24; shift >= 0; shift -= 8) {
#pragma unroll
            for (int i = 0; i < 4; ++i) { bins[i][t] = 0; fbins[i][t] = 0.0f; }
            __syncthreads();
            unsigned pmask = sh_pmask, prefix = sh_prefix;
            unsigned kk = sh_kk;
            if (shift == 24) {
                for (int i = t; i < D; i += 256) {
                    float fv = row[i];
                    if (uselds) ldsrow[i] = fv;
                    unsigned v = __float_as_uint(fv);
                    atomicAdd(&bins[w][v >> 24], 1u);
                    atomicAdd(&fbins[w][v >> 24], fv);
                }
            } else {
                for (int i = t; i < D; i += 256) {
                    float fv = uselds ? ldsrow[i] : row[i];
                    unsigned v = __float_as_uint(fv);
                    if ((v & pmask) == prefix) {
                        atomicAdd(&bins[w][(v >> shift) & 255u], 1u);
                        atomicAdd(&fbins[w][(v >> shift) & 255u], fv);
                    }
                }
            }
            __syncthreads();
            sc[0][t] = bins[0][t] + bins[1][t] + bins[2][t] + bins[3][t];
            sf[0][t] = fbins[0][t] + fbins[1][t] + fbins[2][t] + fbins[3][t];
            __syncthreads();
            int src = 0;
#pragma unroll
            for (int off = 1; off < 256; off <<= 1) {
                int dst = 1 - src;
                unsigned cv = sc[src][t] + ((t + off < 256) ? sc[src][t + off] : 0u);
                float    fv = sf[src][t] + ((t + off < 256) ? sf[src][t + off] : 0.0f);
                sc[dst][t] = cv; sf[dst][t] = fv;
                __syncthreads();
                src = dst;
            }
            unsigned sufc  = sc[src][t];
            unsigned above = (t < 255) ? sc[src][t + 1] : 0u;
            if (sufc >= kk && above < kk) {
                sh_above += (double)((t < 255) ? sf[src][t + 1] : 0.0f);
                sh_kk = kk - above;
                sh_prefix = prefix | ((unsigned)t << shift);
                sh_pmask = pmask | (255u << shift);
            }
            __syncthreads();
        }
        if (t == 0)
            tot = sh_above + (double)sh_kk * (double)__uint_as_float(sh_prefix);
    }
    if (t == 0) negpart[b] = tot;       // plain store (0 if no positives)
}

// ---------------------------------------------------------------------------
// finalize: sum all plain partials -> two output scalars (deterministic)
// ---------------------------------------------------------------------------
__global__ void finalize_kernel(const double* __restrict__ locpart,
                                const double* __restrict__ pospart,
                                const double* __restrict__ negpart,
                                const int*    __restrict__ n_pos,
                                int B, int P, float* __restrict__ out) {
    __shared__ double sl[256], sp[256], sn[256];
    __shared__ int    si[256];
    int t = threadIdx.x;
    double l = 0.0, pp = 0.0, nn = 0.0; int c = 0;
    for (int i = t; i < B; i += 256) { l += locpart[i]; nn += negpart[i]; c += n_pos[i]; }
    for (int i = t; i < P; i += 256) pp += pospart[i];
    sl[t] = l; sp[t] = pp; sn[t] = nn; si[t] = c;
    __syncthreads();
    for (int s = 128; s > 0; s >>= 1) {
        if (t < s) { sl[t] += sl[t+s]; sp[t] += sp[t+s]; sn[t] += sn[t+s]; si[t] += si[t+s]; }
        __syncthreads();
    }
    if (t == 0) {
        double nd = (double)si[0];
        out[0] = (float)(sl[0] / (nd * 4.0));
        out[1] = (float)((sn[0] + sp[0]) / nd);
    }
}

// ---------------------------------------------------------------------------
extern "C" void kernel_launch(void* const* d_in, const int* in_sizes, int n_in,
                              void* d_out, int out_size, void* d_ws, size_t ws_size,
                              hipStream_t stream) {
    const float* locs   = (const float*)d_in[0];
    const float* cls    = (const float*)d_in[1];
    const float* boxes  = (const float*)d_in[2];
    const int*   labels = (const int*)d_in[3];
    const float* dboxes = (const float*)d_in[4];

    int D = in_sizes[4] / 4;
    int B = in_sizes[0] / (4 * D);
    int O = in_sizes[3] / B;
    int C = in_sizes[1] / (B * D);
    int R = B * D;
    const int NCE = 2048;

    char* ws = (char*)d_ws;
    size_t off = 0;
    double* locpart = (double*)(ws + off); off += (size_t)B * 8;
    double* negpart = (double*)(ws + off); off += (size_t)B * 8;
    double* pospart = (double*)(ws + off); off += (size_t)NCE * 8;
    int*    n_pos   = (int*)(ws + off);    off += (size_t)B * 4;
    off = (off + 15) & ~(size_t)15;
    int*    tcls    = (int*)(ws + off);    off += (size_t)R * 4;
    float*  negbuf  = (float*)(ws + off);

    size_t match_sh = (size_t)D * 4 + (size_t)D;   // sOvl + sObj
    match_kernel<<<B, 256, match_sh, stream>>>(boxes, labels, dboxes, locs,
                                               tcls, n_pos, locpart, D, O);
    if (C == 81 && (R % 16) == 0) {
        ce4_kernel<<<NCE, 256, 0, stream>>>(cls, tcls, negbuf, pospart, R);
    } else {
        ce2_kernel<<<NCE, 256, 0, stream>>>(cls, tcls, negbuf, pospart, R, C);
    }
    int uselds = (D * 4 <= 40000) ? 1 : 0;
    size_t shbytes = uselds ? (size_t)D * 4 : 0;
    hardneg_kernel<<<B, 256, shbytes, stream>>>(negbuf, n_pos, negpart, D, uselds);
    finalize_kernel<<<1, 256, 0, stream>>>(locpart, pospart, negpart, n_pos,
                                           B, NCE, (float*)d_out);
}